// Round 20
// baseline (284.392 us; speedup 1.0000x reference)
//
#include <hip/hip_runtime.h>
#include <math.h>

#define NN 1024
#define IN_F 256
#define OUT_F 128
#define NHEADS 4
#define NHF 32
#define ITILE 4
#define HPSTR 260  // h-tile row stride in dwords. Row term gives banks row*4%32,
                   // chunk term is 0 mod 32 -> every ds_read_b128 across 64 lanes
                   // lands exactly 8 dwords/bank = the b128 floor (conflict-free).

typedef float vf2 __attribute__((ext_vector_type(2)));

// R18 base (98.62us, session best) + one new lever: Phase A's gr/attn_w reads
// moved from scalar loads (128 s_load + lgkmcnt waits per c-iter, unhoistable
// at SGPR_Count=112) to LDS broadcast reads staged once per block; all 8 adj
// loads hoisted to kernel start. Session facts: 41us fill is un-ownable
// (R14); fusion refuted (R10 coop no-launch, R13/R17 barrier L2-storm);
// issue-rate and occupancy levers exhausted (R4/R5/R9 invariance).

// K1 v6: g_l = h @ Wl^T, g_r = h @ Wr^T -> [head][row][f] fp32.
// 8-row tiles (8.3 KB LDS), grid 2048 = 128 rowgroups x 16 colsets -> 8 blocks/CU,
// 32 waves/CU. Lanes = 8 rows x 8 k-chunks of 32; W as broadcast VMEM float4;
// packed-fp32 dots; k-chunks folded with 3 shfl_xor. UNCHANGED from R18.
__global__ void __launch_bounds__(256, 8) glr_gemm(const float* __restrict__ hmat,
                                                   const float* __restrict__ Wl,
                                                   const float* __restrict__ Wr,
                                                   float* __restrict__ glh,
                                                   float* __restrict__ grh) {
    __shared__ float hp[8 * HPSTR];  // 8.3 KB
    const int tid = threadIdx.x;
    const int rg = blockIdx.x & 127;  // 128 row-groups of 8 rows
    const int cs = blockIdx.x >> 7;   // 16 col-sets of 16 cols

    // Stage 8 rows x 256 floats, coalesced.
    const float4* __restrict__ hsrc = (const float4*)hmat + rg * (8 * 64);
#pragma unroll
    for (int i = 0; i < 2; ++i) {
        const int v = tid + i * 256;
        const int row = v >> 6, kq = v & 63;
        *(float4*)(hp + row * HPSTR + kq * 4) = hsrc[v];
    }
    __syncthreads();

    const int lane = tid & 63;
    const int row  = lane & 7;        // 8 rows
    const int kc   = lane >> 3;       // 8 k-chunks of 32 floats
    const int wu   = __builtin_amdgcn_readfirstlane(tid >> 6);
    const int c0   = cs * 16 + wu * 4;
    const float* __restrict__ wb = (c0 < OUT_F) ? (Wl + c0 * IN_F)
                                                : (Wr + (c0 - OUT_F) * IN_F);
    const float* __restrict__ hrow = hp + row * HPSTR + kc * 32;
    const float* __restrict__ wrow = wb + kc * 32;

    vf2 a0 = {0.f, 0.f}, a1 = {0.f, 0.f}, a2 = {0.f, 0.f}, a3 = {0.f, 0.f};
#pragma unroll 2
    for (int i = 0; i < 8; ++i) {
        const float4 hv = *(const float4*)(hrow + i * 4);
        const vf2 hA = {hv.x, hv.y};
        const vf2 hB = {hv.z, hv.w};
        const float4 w0 = *(const float4*)(wrow + 0 * IN_F + i * 4);
        const float4 w1 = *(const float4*)(wrow + 1 * IN_F + i * 4);
        const float4 w2 = *(const float4*)(wrow + 2 * IN_F + i * 4);
        const float4 w3 = *(const float4*)(wrow + 3 * IN_F + i * 4);
        a0 = hA * (vf2){w0.x, w0.y} + a0;  a0 = hB * (vf2){w0.z, w0.w} + a0;
        a1 = hA * (vf2){w1.x, w1.y} + a1;  a1 = hB * (vf2){w1.z, w1.w} + a1;
        a2 = hA * (vf2){w2.x, w2.y} + a2;  a2 = hB * (vf2){w2.z, w2.w} + a2;
        a3 = hA * (vf2){w3.x, w3.y} + a3;  a3 = hB * (vf2){w3.z, w3.w} + a3;
    }
    float s0 = a0.x + a0.y, s1 = a1.x + a1.y, s2 = a2.x + a2.y, s3 = a3.x + a3.y;
    // fold the 8 k-chunks (lane bits 3,4,5)
#pragma unroll
    for (int d = 8; d <= 32; d <<= 1) {
        s0 += __shfl_xor(s0, d);
        s1 += __shfl_xor(s1, d);
        s2 += __shfl_xor(s2, d);
        s3 += __shfl_xor(s3, d);
    }

    if (kc == 0) {
        const int cb = c0 & (OUT_F - 1);
        const int hh = cb >> 5;
        const int f  = cb & 31;               // multiple of 4 -> aligned float4 store
        float* __restrict__ dst = (c0 < OUT_F) ? glh : grh;
        float4 r; r.x = s0; r.y = s1; r.z = s2; r.w = s3;
        *(float4*)(dst + (hh * NN + rg * 8 + row) * NHF + f) = r;
    }
}

// K2 v7: R18's v6 + LDS-staged gr/attn_w (broadcast reads replace s_loads in
// the Phase-A hot loop) + early-hoisted adj loads.
__global__ void __launch_bounds__(512, 8) gat_main(const float* __restrict__ glh,
                                                   const float* __restrict__ grh,
                                                   const int* __restrict__ adj,
                                                   const float* __restrict__ attn_w,
                                                   float* __restrict__ out) {
    const int hh  = blockIdx.y;
    const int i0  = blockIdx.x * ITILE;
    const int tid = threadIdx.x;

    __shared__ float p_buf[ITILE][1028];   // stride%32==4 -> optimal b128 banking
    __shared__ float part[ITILE][16][NHF]; // [ii][j-slice][f]
    __shared__ float red[ITILE][8];
    __shared__ float l_sh[ITILE];
    __shared__ float gr_sh[ITILE][NHF];    // 512 B: the 4 gr rows, LDS broadcast
    __shared__ float aw_sh[NHF];           // 128 B

    // ---- hoisted loads: adj for both c-iters (VMEM latency hides under
    // staging + first gl loads), gr tile + attn_w to LDS ----
    int adjv[2][ITILE];
#pragma unroll
    for (int c = 0; c < 2; ++c)
#pragma unroll
        for (int ii = 0; ii < ITILE; ++ii)
            adjv[c][ii] = adj[(i0 + ii) * NN + (c << 9) + tid];

    if (tid < ITILE * NHF)
        gr_sh[tid >> 5][tid & 31] = grh[(hh * NN + i0 + (tid >> 5)) * NHF + (tid & 31)];
    if (tid < NHF) aw_sh[tid] = attn_w[tid];
    __syncthreads();

    float lpart[ITILE];
#pragma unroll
    for (int ii = 0; ii < ITILE; ++ii) lpart[ii] = 0.f;

    // ---- Phase A (e + exp + row-sum fused) ----
#pragma unroll 1
    for (int c = 0; c < 2; ++c) {
        const int j = (c << 9) + tid;
        const float* __restrict__ gp = glh + (hh * NN + j) * NHF;

        vf2 S2[ITILE];
#pragma unroll
        for (int ii = 0; ii < ITILE; ++ii) S2[ii] = (vf2){0.f, 0.f};
        vf2 alpha2 = {0.f, 0.f};

#pragma unroll
        for (int fh = 0; fh < 2; ++fh) {       // f-half loop: only 16 gl floats live
            const int fb = fh << 4;
            vf2 g2[8];
#pragma unroll
            for (int q = 0; q < 4; ++q) {
                const float4 v = *(const float4*)(gp + fb + (q << 2));
                g2[2 * q + 0] = (vf2){v.x, v.y};
                g2[2 * q + 1] = (vf2){v.z, v.w};
            }
#pragma unroll
            for (int k2 = 0; k2 < 8; ++k2) {
                const vf2 w2 = *(const vf2*)(aw_sh + fb + 2 * k2);   // LDS broadcast
                alpha2 = g2[k2] * w2 + alpha2;
            }
#pragma unroll
            for (int ii = 0; ii < ITILE; ++ii) {
                const float* __restrict__ grp = gr_sh[ii] + fb;      // LDS broadcast
                vf2 acc = S2[ii];
#pragma unroll
                for (int k2 = 0; k2 < 8; ++k2) {
                    const vf2 s = g2[k2] + *(const vf2*)(grp + 2 * k2);
                    vf2 a; a.x = fabsf(s.x); a.y = fabsf(s.y);
                    acc = a * (*(const vf2*)(aw_sh + fb + 2 * k2)) + acc;
                }
                S2[ii] = acc;
            }
        }
#pragma unroll
        for (int ii = 0; ii < ITILE; ++ii) {
            const float e = fmaf(0.4f, S2[ii].x + S2[ii].y,
                                 0.6f * (alpha2.x + alpha2.y));
            const float p = adjv[c][ii] ? __expf(e) : 0.f;
            p_buf[ii][j] = p;
            lpart[ii] += p;
        }
    }

    // ---- row-sum reduction ----
    const int lane = tid & 63, wv = tid >> 6;
#pragma unroll
    for (int ii = 0; ii < ITILE; ++ii) {
        float v = lpart[ii];
#pragma unroll
        for (int d = 32; d > 0; d >>= 1) v += __shfl_xor(v, d);
        if (lane == 0) red[ii][wv] = v;
    }
    __syncthreads();
    if (tid < ITILE) {
        float l = red[tid][0];
#pragma unroll
        for (int w = 1; w < 8; ++w) l += red[tid][w];
        l_sh[tid] = l;
    }
    __syncthreads();

    // ---- Phase C: o[ii,f] = sum_j p * g_r (packed over jj-pairs) ----
    const int f  = tid & 31;
    const int js = tid >> 5;                  // 16 j-slices of 64
    const float* __restrict__ gp = grh + hh * NN * NHF + f;
    vf2 o2[ITILE];
#pragma unroll
    for (int ii = 0; ii < ITILE; ++ii) o2[ii] = (vf2){0.f, 0.f};
    const int jb = js << 6;
#pragma unroll 4
    for (int jj = 0; jj < 64; jj += 4) {
        const int j = jb + jj;
        const float g0 = gp[(j + 0) * NHF];
        const float g1 = gp[(j + 1) * NHF];
        const float g2 = gp[(j + 2) * NHF];
        const float g3 = gp[(j + 3) * NHF];
        const vf2 gA = {g0, g1};
        const vf2 gB = {g2, g3};
#pragma unroll
        for (int ii = 0; ii < ITILE; ++ii) {
            const float4 p4 = *(const float4*)&p_buf[ii][j];
            o2[ii] = (vf2){p4.x, p4.y} * gA + o2[ii];
            o2[ii] = (vf2){p4.z, p4.w} * gB + o2[ii];
        }
    }
#pragma unroll
    for (int ii = 0; ii < ITILE; ++ii) part[ii][js][f] = o2[ii].x + o2[ii].y;
    __syncthreads();

    if (tid < 32 * ITILE) {
        const int ii = tid >> 5, ff = tid & 31;
        float s0 = 0.f, s1 = 0.f, s2 = 0.f, s3 = 0.f;
#pragma unroll
        for (int k = 0; k < 16; k += 4) {
            s0 += part[ii][k + 0][ff];
            s1 += part[ii][k + 1][ff];
            s2 += part[ii][k + 2][ff];
            s3 += part[ii][k + 3][ff];
        }
        float s = ((s0 + s1) + (s2 + s3)) / l_sh[ii];
        const float r = (s > 0.f) ? s : (__expf(s) - 1.f);
        out[(i0 + ii) * OUT_F + hh * NHF + ff] = r;
    }
}

extern "C" void kernel_launch(void* const* d_in, const int* in_sizes, int n_in,
                              void* d_out, int out_size, void* d_ws, size_t ws_size,
                              hipStream_t stream) {
    const float* hmat = (const float*)d_in[0];
    const int*   adj  = (const int*)d_in[1];
    const float* Wl   = (const float*)d_in[2];
    const float* Wr   = (const float*)d_in[3];
    const float* aw   = (const float*)d_in[4];
    float* o          = (float*)d_out;

    float* glh = (float*)d_ws;                 // [4][1024][32]
    float* grh = glh + NHEADS * NN * NHF;      // [4][1024][32]

    glr_gemm<<<dim3(2048), dim3(256), 0, stream>>>(hmat, Wl, Wr, glh, grh);
    gat_main<<<dim3(NN / ITILE, NHEADS), dim3(512), 0, stream>>>(glh, grh, adj, aw, o);
}

// Round 22
// 280.555 us; speedup vs baseline: 1.0137x; 1.0137x over previous
//
#include <hip/hip_runtime.h>
#include <math.h>

#define NN 1024
#define IN_F 256
#define OUT_F 128
#define NHEADS 4
#define NHF 32
#define ITILE 4
#define HPSTR 260  // h-tile row stride in dwords. Row term gives banks row*4%32,
                   // chunk term is 0 mod 32 -> every ds_read_b128 across 64 lanes
                   // lands exactly 8 dwords/bank = the b128 floor (conflict-free).

typedef float vf2 __attribute__((ext_vector_type(2)));

// R20 postmortem: v7's adjv[2][4] hoist (8 regs live across all of Phase A)
// tripped the (512,8) 64-VGPR cap -> wholesale spill (VGPR_Count=32, 331MB
// FETCH / 349MB WRITE scratch traffic, 216us). Third spill event of the
// session (R4, R13, R20) -- signature is always VGPR_Count collapse + 100s of
// MB of FETCH/WRITE. This version: EXACT R18 v6 structure (98.62us best) with
// the ONE untested change isolated: Phase A's gr/attn_w reads via LDS
// broadcast (staged once/block) instead of in-loop s_loads. adj loads stay
// per-c-iter as in v6. Register pressure <= v6 -> no spill risk.

// K1 v6: g_l = h @ Wl^T, g_r = h @ Wr^T -> [head][row][f] fp32.
// 8-row tiles (8.3 KB LDS), grid 2048 = 128 rowgroups x 16 colsets -> 8 blocks/CU,
// 32 waves/CU. Lanes = 8 rows x 8 k-chunks of 32; W as broadcast VMEM float4;
// packed-fp32 dots; k-chunks folded with 3 shfl_xor. UNCHANGED from R18.
__global__ void __launch_bounds__(256, 8) glr_gemm(const float* __restrict__ hmat,
                                                   const float* __restrict__ Wl,
                                                   const float* __restrict__ Wr,
                                                   float* __restrict__ glh,
                                                   float* __restrict__ grh) {
    __shared__ float hp[8 * HPSTR];  // 8.3 KB
    const int tid = threadIdx.x;
    const int rg = blockIdx.x & 127;  // 128 row-groups of 8 rows
    const int cs = blockIdx.x >> 7;   // 16 col-sets of 16 cols

    // Stage 8 rows x 256 floats, coalesced.
    const float4* __restrict__ hsrc = (const float4*)hmat + rg * (8 * 64);
#pragma unroll
    for (int i = 0; i < 2; ++i) {
        const int v = tid + i * 256;
        const int row = v >> 6, kq = v & 63;
        *(float4*)(hp + row * HPSTR + kq * 4) = hsrc[v];
    }
    __syncthreads();

    const int lane = tid & 63;
    const int row  = lane & 7;        // 8 rows
    const int kc   = lane >> 3;       // 8 k-chunks of 32 floats
    const int wu   = __builtin_amdgcn_readfirstlane(tid >> 6);
    const int c0   = cs * 16 + wu * 4;
    const float* __restrict__ wb = (c0 < OUT_F) ? (Wl + c0 * IN_F)
                                                : (Wr + (c0 - OUT_F) * IN_F);
    const float* __restrict__ hrow = hp + row * HPSTR + kc * 32;
    const float* __restrict__ wrow = wb + kc * 32;

    vf2 a0 = {0.f, 0.f}, a1 = {0.f, 0.f}, a2 = {0.f, 0.f}, a3 = {0.f, 0.f};
#pragma unroll 2
    for (int i = 0; i < 8; ++i) {
        const float4 hv = *(const float4*)(hrow + i * 4);
        const vf2 hA = {hv.x, hv.y};
        const vf2 hB = {hv.z, hv.w};
        const float4 w0 = *(const float4*)(wrow + 0 * IN_F + i * 4);
        const float4 w1 = *(const float4*)(wrow + 1 * IN_F + i * 4);
        const float4 w2 = *(const float4*)(wrow + 2 * IN_F + i * 4);
        const float4 w3 = *(const float4*)(wrow + 3 * IN_F + i * 4);
        a0 = hA * (vf2){w0.x, w0.y} + a0;  a0 = hB * (vf2){w0.z, w0.w} + a0;
        a1 = hA * (vf2){w1.x, w1.y} + a1;  a1 = hB * (vf2){w1.z, w1.w} + a1;
        a2 = hA * (vf2){w2.x, w2.y} + a2;  a2 = hB * (vf2){w2.z, w2.w} + a2;
        a3 = hA * (vf2){w3.x, w3.y} + a3;  a3 = hB * (vf2){w3.z, w3.w} + a3;
    }
    float s0 = a0.x + a0.y, s1 = a1.x + a1.y, s2 = a2.x + a2.y, s3 = a3.x + a3.y;
    // fold the 8 k-chunks (lane bits 3,4,5)
#pragma unroll
    for (int d = 8; d <= 32; d <<= 1) {
        s0 += __shfl_xor(s0, d);
        s1 += __shfl_xor(s1, d);
        s2 += __shfl_xor(s2, d);
        s3 += __shfl_xor(s3, d);
    }

    if (kc == 0) {
        const int cb = c0 & (OUT_F - 1);
        const int hh = cb >> 5;
        const int f  = cb & 31;               // multiple of 4 -> aligned float4 store
        float* __restrict__ dst = (c0 < OUT_F) ? glh : grh;
        float4 r; r.x = s0; r.y = s1; r.z = s2; r.w = s3;
        *(float4*)(dst + (hh * NN + rg * 8 + row) * NHF + f) = r;
    }
}

// K2 v8: R18 v6 + LDS-staged gr/attn_w ONLY (adj loads per-c-iter, unhosted).
__global__ void __launch_bounds__(512, 8) gat_main(const float* __restrict__ glh,
                                                   const float* __restrict__ grh,
                                                   const int* __restrict__ adj,
                                                   const float* __restrict__ attn_w,
                                                   float* __restrict__ out) {
    const int hh  = blockIdx.y;
    const int i0  = blockIdx.x * ITILE;
    const int tid = threadIdx.x;

    __shared__ float p_buf[ITILE][1028];   // stride%32==4 -> optimal b128 banking
    __shared__ float part[ITILE][16][NHF]; // [ii][j-slice][f]
    __shared__ float red[ITILE][8];
    __shared__ float l_sh[ITILE];
    __shared__ float gr_sh[ITILE][NHF];    // 512 B: the 4 gr rows, LDS broadcast
    __shared__ float aw_sh[NHF];           // 128 B

    // Stage gr tile + attn_w once per block (lanes-same-address reads later
    // are conflict-free broadcasts).
    if (tid < ITILE * NHF)
        gr_sh[tid >> 5][tid & 31] = grh[(hh * NN + i0 + (tid >> 5)) * NHF + (tid & 31)];
    if (tid < NHF) aw_sh[tid] = attn_w[tid];
    __syncthreads();

    float lpart[ITILE];
#pragma unroll
    for (int ii = 0; ii < ITILE; ++ii) lpart[ii] = 0.f;

    // ---- Phase A (e + exp + row-sum fused) ----
#pragma unroll 1
    for (int c = 0; c < 2; ++c) {
        const int j = (c << 9) + tid;
        const float* __restrict__ gp = glh + (hh * NN + j) * NHF;
        int adjv[ITILE];
#pragma unroll
        for (int ii = 0; ii < ITILE; ++ii) adjv[ii] = adj[(i0 + ii) * NN + j];

        vf2 S2[ITILE];
#pragma unroll
        for (int ii = 0; ii < ITILE; ++ii) S2[ii] = (vf2){0.f, 0.f};
        vf2 alpha2 = {0.f, 0.f};

#pragma unroll
        for (int fh = 0; fh < 2; ++fh) {       // f-half loop: only 16 gl floats live
            const int fb = fh << 4;
            vf2 g2[8];
#pragma unroll
            for (int q = 0; q < 4; ++q) {
                const float4 v = *(const float4*)(gp + fb + (q << 2));
                g2[2 * q + 0] = (vf2){v.x, v.y};
                g2[2 * q + 1] = (vf2){v.z, v.w};
            }
#pragma unroll
            for (int k2 = 0; k2 < 8; ++k2) {
                const vf2 w2 = *(const vf2*)(aw_sh + fb + 2 * k2);   // LDS broadcast
                alpha2 = g2[k2] * w2 + alpha2;
            }
#pragma unroll
            for (int ii = 0; ii < ITILE; ++ii) {
                const float* __restrict__ grp = gr_sh[ii] + fb;      // LDS broadcast
                vf2 acc = S2[ii];
#pragma unroll
                for (int k2 = 0; k2 < 8; ++k2) {
                    const vf2 s = g2[k2] + *(const vf2*)(grp + 2 * k2);
                    vf2 a; a.x = fabsf(s.x); a.y = fabsf(s.y);
                    acc = a * (*(const vf2*)(aw_sh + fb + 2 * k2)) + acc;
                }
                S2[ii] = acc;
            }
        }
#pragma unroll
        for (int ii = 0; ii < ITILE; ++ii) {
            const float e = fmaf(0.4f, S2[ii].x + S2[ii].y,
                                 0.6f * (alpha2.x + alpha2.y));
            const float p = adjv[ii] ? __expf(e) : 0.f;
            p_buf[ii][j] = p;
            lpart[ii] += p;
        }
    }

    // ---- row-sum reduction ----
    const int lane = tid & 63, wv = tid >> 6;
#pragma unroll
    for (int ii = 0; ii < ITILE; ++ii) {
        float v = lpart[ii];
#pragma unroll
        for (int d = 32; d > 0; d >>= 1) v += __shfl_xor(v, d);
        if (lane == 0) red[ii][wv] = v;
    }
    __syncthreads();
    if (tid < ITILE) {
        float l = red[tid][0];
#pragma unroll
        for (int w = 1; w < 8; ++w) l += red[tid][w];
        l_sh[tid] = l;
    }
    __syncthreads();

    // ---- Phase C: o[ii,f] = sum_j p * g_r (packed over jj-pairs) ----
    const int f  = tid & 31;
    const int js = tid >> 5;                  // 16 j-slices of 64
    const float* __restrict__ gp = grh + hh * NN * NHF + f;
    vf2 o2[ITILE];
#pragma unroll
    for (int ii = 0; ii < ITILE; ++ii) o2[ii] = (vf2){0.f, 0.f};
    const int jb = js << 6;
#pragma unroll 4
    for (int jj = 0; jj < 64; jj += 4) {
        const int j = jb + jj;
        const float g0 = gp[(j + 0) * NHF];
        const float g1 = gp[(j + 1) * NHF];
        const float g2 = gp[(j + 2) * NHF];
        const float g3 = gp[(j + 3) * NHF];
        const vf2 gA = {g0, g1};
        const vf2 gB = {g2, g3};
#pragma unroll
        for (int ii = 0; ii < ITILE; ++ii) {
            const float4 p4 = *(const float4*)&p_buf[ii][j];
            o2[ii] = (vf2){p4.x, p4.y} * gA + o2[ii];
            o2[ii] = (vf2){p4.z, p4.w} * gB + o2[ii];
        }
    }
#pragma unroll
    for (int ii = 0; ii < ITILE; ++ii) part[ii][js][f] = o2[ii].x + o2[ii].y;
    __syncthreads();

    if (tid < 32 * ITILE) {
        const int ii = tid >> 5, ff = tid & 31;
        float s0 = 0.f, s1 = 0.f, s2 = 0.f, s3 = 0.f;
#pragma unroll
        for (int k = 0; k < 16; k += 4) {
            s0 += part[ii][k + 0][ff];
            s1 += part[ii][k + 1][ff];
            s2 += part[ii][k + 2][ff];
            s3 += part[ii][k + 3][ff];
        }
        float s = ((s0 + s1) + (s2 + s3)) / l_sh[ii];
        const float r = (s > 0.f) ? s : (__expf(s) - 1.f);
        out[(i0 + ii) * OUT_F + hh * NHF + ff] = r;
    }
}

extern "C" void kernel_launch(void* const* d_in, const int* in_sizes, int n_in,
                              void* d_out, int out_size, void* d_ws, size_t ws_size,
                              hipStream_t stream) {
    const float* hmat = (const float*)d_in[0];
    const int*   adj  = (const int*)d_in[1];
    const float* Wl   = (const float*)d_in[2];
    const float* Wr   = (const float*)d_in[3];
    const float* aw   = (const float*)d_in[4];
    float* o          = (float*)d_out;

    float* glh = (float*)d_ws;                 // [4][1024][32]
    float* grh = glh + NHEADS * NN * NHF;      // [4][1024][32]

    glr_gemm<<<dim3(2048), dim3(256), 0, stream>>>(hmat, Wl, Wr, glh, grh);
    gat_main<<<dim3(NN / ITILE, NHEADS), dim3(512), 0, stream>>>(glh, grh, adj, aw, o);
}

// Round 23
// 161.844 us; speedup vs baseline: 1.7572x; 1.7335x over previous
//
#include <hip/hip_runtime.h>
#include <math.h>

#define NN 1024
#define IN_F 256
#define OUT_F 128
#define NHEADS 4
#define NHF 32
#define ITILE 4
#define HPSTR 260  // h-tile row stride in dwords. Row term gives banks row*4%32,
                   // chunk term is 0 mod 32 -> every ds_read_b128 across 64 lanes
                   // lands exactly 8 dwords/bank = the b128 floor (conflict-free).

typedef float vf2 __attribute__((ext_vector_type(2)));

// R22 postmortem: v8 spilled too (VGPR_Count=32, 301/321MB scratch, 4th spill
// of the session). Mechanism finally clear: v6's grp/attn_w reads were s_loads
// into SGPRs (112 used, plentiful); LDS-ifying them moved that working set
// into VGPRs and blew the (512,8) 64-VGPR cap. Fix: SAME v8 body at
// launch_bounds(512,4) -> 128-VGPR cap, no spill, 2 blocks/CU (16 waves/CU --
// measured-free: R2 at 16 waves/CU == R4 at 32 waves/CU, both 42us).

// K1 v6: g_l = h @ Wl^T, g_r = h @ Wr^T -> [head][row][f] fp32. UNCHANGED.
__global__ void __launch_bounds__(256, 8) glr_gemm(const float* __restrict__ hmat,
                                                   const float* __restrict__ Wl,
                                                   const float* __restrict__ Wr,
                                                   float* __restrict__ glh,
                                                   float* __restrict__ grh) {
    __shared__ float hp[8 * HPSTR];  // 8.3 KB
    const int tid = threadIdx.x;
    const int rg = blockIdx.x & 127;  // 128 row-groups of 8 rows
    const int cs = blockIdx.x >> 7;   // 16 col-sets of 16 cols

    // Stage 8 rows x 256 floats, coalesced.
    const float4* __restrict__ hsrc = (const float4*)hmat + rg * (8 * 64);
#pragma unroll
    for (int i = 0; i < 2; ++i) {
        const int v = tid + i * 256;
        const int row = v >> 6, kq = v & 63;
        *(float4*)(hp + row * HPSTR + kq * 4) = hsrc[v];
    }
    __syncthreads();

    const int lane = tid & 63;
    const int row  = lane & 7;        // 8 rows
    const int kc   = lane >> 3;       // 8 k-chunks of 32 floats
    const int wu   = __builtin_amdgcn_readfirstlane(tid >> 6);
    const int c0   = cs * 16 + wu * 4;
    const float* __restrict__ wb = (c0 < OUT_F) ? (Wl + c0 * IN_F)
                                                : (Wr + (c0 - OUT_F) * IN_F);
    const float* __restrict__ hrow = hp + row * HPSTR + kc * 32;
    const float* __restrict__ wrow = wb + kc * 32;

    vf2 a0 = {0.f, 0.f}, a1 = {0.f, 0.f}, a2 = {0.f, 0.f}, a3 = {0.f, 0.f};
#pragma unroll 2
    for (int i = 0; i < 8; ++i) {
        const float4 hv = *(const float4*)(hrow + i * 4);
        const vf2 hA = {hv.x, hv.y};
        const vf2 hB = {hv.z, hv.w};
        const float4 w0 = *(const float4*)(wrow + 0 * IN_F + i * 4);
        const float4 w1 = *(const float4*)(wrow + 1 * IN_F + i * 4);
        const float4 w2 = *(const float4*)(wrow + 2 * IN_F + i * 4);
        const float4 w3 = *(const float4*)(wrow + 3 * IN_F + i * 4);
        a0 = hA * (vf2){w0.x, w0.y} + a0;  a0 = hB * (vf2){w0.z, w0.w} + a0;
        a1 = hA * (vf2){w1.x, w1.y} + a1;  a1 = hB * (vf2){w1.z, w1.w} + a1;
        a2 = hA * (vf2){w2.x, w2.y} + a2;  a2 = hB * (vf2){w2.z, w2.w} + a2;
        a3 = hA * (vf2){w3.x, w3.y} + a3;  a3 = hB * (vf2){w3.z, w3.w} + a3;
    }
    float s0 = a0.x + a0.y, s1 = a1.x + a1.y, s2 = a2.x + a2.y, s3 = a3.x + a3.y;
    // fold the 8 k-chunks (lane bits 3,4,5)
#pragma unroll
    for (int d = 8; d <= 32; d <<= 1) {
        s0 += __shfl_xor(s0, d);
        s1 += __shfl_xor(s1, d);
        s2 += __shfl_xor(s2, d);
        s3 += __shfl_xor(s3, d);
    }

    if (kc == 0) {
        const int cb = c0 & (OUT_F - 1);
        const int hh = cb >> 5;
        const int f  = cb & 31;               // multiple of 4 -> aligned float4 store
        float* __restrict__ dst = (c0 < OUT_F) ? glh : grh;
        float4 r; r.x = s0; r.y = s1; r.z = s2; r.w = s3;
        *(float4*)(dst + (hh * NN + rg * 8 + row) * NHF + f) = r;
    }
}

// K2 v9: v8 body (LDS-staged gr/attn_w) at launch_bounds(512,4) -> no spill.
__global__ void __launch_bounds__(512, 4) gat_main(const float* __restrict__ glh,
                                                   const float* __restrict__ grh,
                                                   const int* __restrict__ adj,
                                                   const float* __restrict__ attn_w,
                                                   float* __restrict__ out) {
    const int hh  = blockIdx.y;
    const int i0  = blockIdx.x * ITILE;
    const int tid = threadIdx.x;

    __shared__ float p_buf[ITILE][1028];   // stride%32==4 -> optimal b128 banking
    __shared__ float part[ITILE][16][NHF]; // [ii][j-slice][f]
    __shared__ float red[ITILE][8];
    __shared__ float l_sh[ITILE];
    __shared__ float gr_sh[ITILE][NHF];    // 512 B: the 4 gr rows, LDS broadcast
    __shared__ float aw_sh[NHF];           // 128 B

    // Stage gr tile + attn_w once per block (lanes-same-address reads later
    // are conflict-free broadcasts).
    if (tid < ITILE * NHF)
        gr_sh[tid >> 5][tid & 31] = grh[(hh * NN + i0 + (tid >> 5)) * NHF + (tid & 31)];
    if (tid < NHF) aw_sh[tid] = attn_w[tid];
    __syncthreads();

    float lpart[ITILE];
#pragma unroll
    for (int ii = 0; ii < ITILE; ++ii) lpart[ii] = 0.f;

    // ---- Phase A (e + exp + row-sum fused) ----
#pragma unroll 1
    for (int c = 0; c < 2; ++c) {
        const int j = (c << 9) + tid;
        const float* __restrict__ gp = glh + (hh * NN + j) * NHF;
        int adjv[ITILE];
#pragma unroll
        for (int ii = 0; ii < ITILE; ++ii) adjv[ii] = adj[(i0 + ii) * NN + j];

        vf2 S2[ITILE];
#pragma unroll
        for (int ii = 0; ii < ITILE; ++ii) S2[ii] = (vf2){0.f, 0.f};
        vf2 alpha2 = {0.f, 0.f};

#pragma unroll
        for (int fh = 0; fh < 2; ++fh) {       // f-half loop: only 16 gl floats live
            const int fb = fh << 4;
            vf2 g2[8];
#pragma unroll
            for (int q = 0; q < 4; ++q) {
                const float4 v = *(const float4*)(gp + fb + (q << 2));
                g2[2 * q + 0] = (vf2){v.x, v.y};
                g2[2 * q + 1] = (vf2){v.z, v.w};
            }
#pragma unroll
            for (int k2 = 0; k2 < 8; ++k2) {
                const vf2 w2 = *(const vf2*)(aw_sh + fb + 2 * k2);   // LDS broadcast
                alpha2 = g2[k2] * w2 + alpha2;
            }
#pragma unroll
            for (int ii = 0; ii < ITILE; ++ii) {
                const float* __restrict__ grp = gr_sh[ii] + fb;      // LDS broadcast
                vf2 acc = S2[ii];
#pragma unroll
                for (int k2 = 0; k2 < 8; ++k2) {
                    const vf2 s = g2[k2] + *(const vf2*)(grp + 2 * k2);
                    vf2 a; a.x = fabsf(s.x); a.y = fabsf(s.y);
                    acc = a * (*(const vf2*)(aw_sh + fb + 2 * k2)) + acc;
                }
                S2[ii] = acc;
            }
        }
#pragma unroll
        for (int ii = 0; ii < ITILE; ++ii) {
            const float e = fmaf(0.4f, S2[ii].x + S2[ii].y,
                                 0.6f * (alpha2.x + alpha2.y));
            const float p = adjv[ii] ? __expf(e) : 0.f;
            p_buf[ii][j] = p;
            lpart[ii] += p;
        }
    }

    // ---- row-sum reduction ----
    const int lane = tid & 63, wv = tid >> 6;
#pragma unroll
    for (int ii = 0; ii < ITILE; ++ii) {
        float v = lpart[ii];
#pragma unroll
        for (int d = 32; d > 0; d >>= 1) v += __shfl_xor(v, d);
        if (lane == 0) red[ii][wv] = v;
    }
    __syncthreads();
    if (tid < ITILE) {
        float l = red[tid][0];
#pragma unroll
        for (int w = 1; w < 8; ++w) l += red[tid][w];
        l_sh[tid] = l;
    }
    __syncthreads();

    // ---- Phase C: o[ii,f] = sum_j p * g_r (packed over jj-pairs) ----
    const int f  = tid & 31;
    const int js = tid >> 5;                  // 16 j-slices of 64
    const float* __restrict__ gp = grh + hh * NN * NHF + f;
    vf2 o2[ITILE];
#pragma unroll
    for (int ii = 0; ii < ITILE; ++ii) o2[ii] = (vf2){0.f, 0.f};
    const int jb = js << 6;
#pragma unroll 4
    for (int jj = 0; jj < 64; jj += 4) {
        const int j = jb + jj;
        const float g0 = gp[(j + 0) * NHF];
        const float g1 = gp[(j + 1) * NHF];
        const float g2 = gp[(j + 2) * NHF];
        const float g3 = gp[(j + 3) * NHF];
        const vf2 gA = {g0, g1};
        const vf2 gB = {g2, g3};
#pragma unroll
        for (int ii = 0; ii < ITILE; ++ii) {
            const float4 p4 = *(const float4*)&p_buf[ii][j];
            o2[ii] = (vf2){p4.x, p4.y} * gA + o2[ii];
            o2[ii] = (vf2){p4.z, p4.w} * gB + o2[ii];
        }
    }
#pragma unroll
    for (int ii = 0; ii < ITILE; ++ii) part[ii][js][f] = o2[ii].x + o2[ii].y;
    __syncthreads();

    if (tid < 32 * ITILE) {
        const int ii = tid >> 5, ff = tid & 31;
        float s0 = 0.f, s1 = 0.f, s2 = 0.f, s3 = 0.f;
#pragma unroll
        for (int k = 0; k < 16; k += 4) {
            s0 += part[ii][k + 0][ff];
            s1 += part[ii][k + 1][ff];
            s2 += part[ii][k + 2][ff];
            s3 += part[ii][k + 3][ff];
        }
        float s = ((s0 + s1) + (s2 + s3)) / l_sh[ii];
        const float r = (s > 0.f) ? s : (__expf(s) - 1.f);
        out[(i0 + ii) * OUT_F + hh * NHF + ff] = r;
    }
}

extern "C" void kernel_launch(void* const* d_in, const int* in_sizes, int n_in,
                              void* d_out, int out_size, void* d_ws, size_t ws_size,
                              hipStream_t stream) {
    const float* hmat = (const float*)d_in[0];
    const int*   adj  = (const int*)d_in[1];
    const float* Wl   = (const float*)d_in[2];
    const float* Wr   = (const float*)d_in[3];
    const float* aw   = (const float*)d_in[4];
    float* o          = (float*)d_out;

    float* glh = (float*)d_ws;                 // [4][1024][32]
    float* grh = glh + NHEADS * NN * NHF;      // [4][1024][32]

    glr_gemm<<<dim3(2048), dim3(256), 0, stream>>>(hmat, Wl, Wr, glh, grh);
    gat_main<<<dim3(NN / ITILE, NHEADS), dim3(512), 0, stream>>>(glh, grh, adj, aw, o);
}